// Round 18
// baseline (421.946 us; speedup 1.0000x reference)
//
#include <hip/hip_runtime.h>
#include <hip/hip_bf16.h>

#define NN 100000      // nodes
#define NE 3200000     // edges
#define NF 256         // features
#define CHUNK 512      // staged edges per block iteration
#define GEMM_BLOCKS 1250          // NN/80
#define RP_BLOCKS   1563          // ceil((NE/8)/320)

typedef __attribute__((ext_vector_type(8))) __bf16 bf16x8;
typedef __attribute__((ext_vector_type(4))) float  f32x4;
typedef __attribute__((ext_vector_type(2))) float  f32x2;
typedef __attribute__((ext_vector_type(4))) int    i32x4;

// Sharded table layout: tabS[shard s][node][32 B], shard slice = 3.2 MB (fits
// one XCD's 4 MB L2). Byte b=2c+h of a shard-row holds feature (s+8h)*16+c,
// stored BIASED u8 (q+128). spmm blocks with blockIdx%8==s touch only slice s
// (blockIdx round-robins over XCDs) -> gathers are L2 hits.

// ---- prep: W -> per-lane MFMA B-fragments (bf16) ----
__global__ __launch_bounds__(256) void prep_w(const float* __restrict__ w,
                                              __bf16* __restrict__ wfrag) {
    const int t = blockIdx.x * 256 + threadIdx.x;   // 8192 total
    const int lane = t & 63;
    const int nf   = (t >> 6) & 15;
    const int ks   = t >> 10;
    const int col  = nf * 16 + (lane & 15);
    const int k0   = ks * 32 + (lane >> 4) * 8;
    bf16x8 v;
#pragma unroll
    for (int j = 0; j < 8; ++j) v[j] = (__bf16)w[(k0 + j) * NF + col];
    reinterpret_cast<bf16x8*>(wfrag)[t] = v;
}

// ---- fused GEMM + u8 quantize (B LDS-staged) + rowptr rider blocks ----
__global__ __launch_bounds__(320) void gemm_q(const float* __restrict__ x,
                                              const __bf16* __restrict__ wfrag,
                                              unsigned char* __restrict__ tabS,
                                              float* __restrict__ scales,
                                              const int* __restrict__ erow,
                                              int* __restrict__ rowptr) {
    if (blockIdx.x >= GEMM_BLOCKS) {             // rowptr rider: 8 edges/thread
        const int t8 = (blockIdx.x - GEMM_BLOCKS) * 320 + threadIdx.x;
        if (t8 >= NE / 8) return;
        const int base = t8 * 8;
        const i32x4 c0 = *reinterpret_cast<const i32x4*>(erow + base);
        const i32x4 c1 = *reinterpret_cast<const i32x4*>(erow + base + 4);
        const int E[8] = {c0.x, c0.y, c0.z, c0.w, c1.x, c1.y, c1.z, c1.w};
        int prev = (base == 0) ? -1 : erow[base - 1];
#pragma unroll
        for (int j = 0; j < 8; ++j) {
            const int r = E[j];
            for (int q = prev + 1; q <= r; ++q) rowptr[q] = base + j;
            prev = r;
        }
        if (base + 8 == NE) {
            for (int q = prev + 1; q <= NN; ++q) rowptr[q] = NE;
        }
        return;
    }

    __shared__ __align__(16) __bf16 As[80 * 72];   // 11.5 KB, row stride 144 B
    __shared__ __align__(16) bf16x8 Bs[2048];      // 32 KB: one phase's B-slice

    const int t    = threadIdx.x;
    const int wv   = t >> 6;
    const int lane = t & 63;
    const int row0 = blockIdx.x * 80;

    f32x4 acc[16];
#pragma unroll
    for (int nf = 0; nf < 16; ++nf) acc[nf] = (f32x4){0.f, 0.f, 0.f, 0.f};

    const int    srow = t >> 2;
    const int    sc   = (t & 3) * 16;
    const float* xp   = x + (size_t)(row0 + srow) * NF + sc;
    char* const  wr   = reinterpret_cast<char*>(As) + srow * 144 + sc * 2;

    const char* const rd =
        reinterpret_cast<const char*>(As) + (wv * 16 + (lane & 15)) * 144 + ((lane >> 4) << 4);

    const bf16x8* wf = reinterpret_cast<const bf16x8*>(wfrag);

    f32x4 s0 = __builtin_nontemporal_load(reinterpret_cast<const f32x4*>(xp));
    f32x4 s1 = __builtin_nontemporal_load(reinterpret_cast<const f32x4*>(xp + 4));
    f32x4 s2 = __builtin_nontemporal_load(reinterpret_cast<const f32x4*>(xp + 8));
    f32x4 s3 = __builtin_nontemporal_load(reinterpret_cast<const f32x4*>(xp + 12));

    for (int p = 0; p < 4; ++p) {
        // stage this phase's 32 KB B-slice (contiguous, coalesced, L2-hot)
        for (int i = t; i < 2048; i += 320) Bs[i] = wf[p * 2048 + i];

        bf16x8 b0, b1;
        b0[0] = (__bf16)s0.x; b0[1] = (__bf16)s0.y; b0[2] = (__bf16)s0.z; b0[3] = (__bf16)s0.w;
        b0[4] = (__bf16)s1.x; b0[5] = (__bf16)s1.y; b0[6] = (__bf16)s1.z; b0[7] = (__bf16)s1.w;
        b1[0] = (__bf16)s2.x; b1[1] = (__bf16)s2.y; b1[2] = (__bf16)s2.z; b1[3] = (__bf16)s2.w;
        b1[4] = (__bf16)s3.x; b1[5] = (__bf16)s3.y; b1[6] = (__bf16)s3.z; b1[7] = (__bf16)s3.w;
        *reinterpret_cast<bf16x8*>(wr)      = b0;   // ds_write_b128
        *reinterpret_cast<bf16x8*>(wr + 16) = b1;
        __syncthreads();

        if (p < 3) {
            const float* nx = xp + (p + 1) * 64;
            s0 = __builtin_nontemporal_load(reinterpret_cast<const f32x4*>(nx));
            s1 = __builtin_nontemporal_load(reinterpret_cast<const f32x4*>(nx + 4));
            s2 = __builtin_nontemporal_load(reinterpret_cast<const f32x4*>(nx + 8));
            s3 = __builtin_nontemporal_load(reinterpret_cast<const f32x4*>(nx + 12));
        }

        const bf16x8 af0 = *reinterpret_cast<const bf16x8*>(rd);        // ksub 0
        const bf16x8 af1 = *reinterpret_cast<const bf16x8*>(rd + 64);   // ksub 1
#pragma unroll
        for (int nf = 0; nf < 16; ++nf) {
            const bf16x8 w0 = Bs[(0 * 16 + nf) * 64 + lane];            // ds_read_b128
            acc[nf] = __builtin_amdgcn_mfma_f32_16x16x32_bf16(af0, w0, acc[nf], 0, 0, 0);
        }
#pragma unroll
        for (int nf = 0; nf < 16; ++nf) {
            const bf16x8 w1 = Bs[(1 * 16 + nf) * 64 + lane];
            acc[nf] = __builtin_amdgcn_mfma_f32_16x16x32_bf16(af1, w1, acc[nf], 0, 0, 0);
        }
        __syncthreads();
    }

    // Epilogue: per-row absmax -> biased u8, 8 u16 stores/row into shard slices.
    const int hi   = lane >> 4;
    const int ccol = lane & 15;

    float m[4];
#pragma unroll
    for (int r = 0; r < 4; ++r) {
        float mm = 0.f;
#pragma unroll
        for (int nf = 0; nf < 16; ++nf) mm = fmaxf(mm, fabsf(acc[nf][r]));
        m[r] = mm;
    }
#pragma unroll
    for (int w = 1; w < 16; w <<= 1) {
#pragma unroll
        for (int r = 0; r < 4; ++r) m[r] = fmaxf(m[r], __shfl_xor(m[r], w, 64));
    }

#pragma unroll
    for (int r = 0; r < 4; ++r) {
        const int   node = row0 + wv * 16 + hi * 4 + r;
        const float isc  = 127.0f / fmaxf(m[r], 1e-30f);
        unsigned int qb[16];
#pragma unroll
        for (int nf = 0; nf < 16; ++nf)
            qb[nf] = (unsigned int)(((int)rintf(acc[nf][r] * isc) + 128) & 0xff);
#pragma unroll
        for (int sh = 0; sh < 8; ++sh) {
            const unsigned short u16v = (unsigned short)(qb[sh] | (qb[sh + 8] << 8));
            *reinterpret_cast<unsigned short*>(
                tabS + ((size_t)sh * NN + node) * 32 + ccol * 2) = u16v;
        }
        if (ccol == 0) scales[node] = m[r] * (1.0f / 127.0f);
    }
}

// ---- spmm sharded: blockIdx%8 = shard (XCD-pinned 3.2 MB slice, L2-hit gathers)
// Wave = 1 row; lane = (group g = lane>>3 -> edge, chunk u = lane&7 -> 4 feats).
// 8 edges per gather instr; xor-tree reduce over groups; lanes 0-7 store.
__global__ __launch_bounds__(256) void spmm_s(const unsigned char* __restrict__ tabS,
                                              const int* __restrict__ rowptr,
                                              const int* __restrict__ ecol,
                                              const float* __restrict__ eval,
                                              const float* __restrict__ scales,
                                              const float* __restrict__ bias,
                                              float* __restrict__ out) {
    __shared__ int2 buf[CHUNK];

    const int sh   = blockIdx.x & 7;          // round-robins over the 8 XCDs
    const int rg   = blockIdx.x >> 3;
    const int wave = threadIdx.x >> 6;
    const int lane = threadIdx.x & 63;
    const int g    = lane >> 3;
    const int u    = lane & 7;
    const int row  = rg * 4 + wave;

    const int bs   = rowptr[rg * 4];
    const int bend = rowptr[rg * 4 + 4];
    const int rs   = rowptr[row];
    const int re   = rowptr[row + 1];

    const unsigned char* ts = tabS + (size_t)sh * NN * 32;

    float a0 = 0.f, a1 = 0.f, a2 = 0.f, a3 = 0.f, S = 0.f;

    for (int cs = bs; cs < bend; cs += CHUNK) {
        const int cnt = min(CHUNK, bend - cs);
        if (cs != bs) __syncthreads();
        for (int j = threadIdx.x; j < cnt; j += 256) {
            const int   c = __builtin_nontemporal_load(ecol + cs + j);  // stream
            const float v = __builtin_nontemporal_load(eval + cs + j);  // stream
            buf[j] = make_int2(c, __float_as_int(v * scales[c]));       // scales L2-hot
        }
        __syncthreads();

        const int lo = max(rs, cs);
        const int hi = min(re, cs + cnt);
#pragma unroll 2
        for (int i = lo; i < hi; i += 8) {
            const int  idx = i + g;
            const bool act = idx < hi;
            const int2 p = buf[(act ? idx : lo) - cs];      // ds_read, 8 bcast addrs
            const float v = act ? __int_as_float(p.y) : 0.f;
            const unsigned int gg = *reinterpret_cast<const unsigned int*>(
                ts + (size_t)(unsigned)p.x * 32 + u * 4);   // L2-hit gather
            a0 = fmaf(v, (float)(gg & 0xffu), a0);
            a1 = fmaf(v, (float)((gg >> 8) & 0xffu), a1);
            a2 = fmaf(v, (float)((gg >> 16) & 0xffu), a2);
            a3 = fmaf(v, (float)(gg >> 24), a3);
            S += v;
        }
    }

    // reduce across the 8 edge-groups (lanes with equal u share features)
#pragma unroll
    for (int d = 8; d < 64; d <<= 1) {
        a0 += __shfl_xor(a0, d, 64);
        a1 += __shfl_xor(a1, d, 64);
        a2 += __shfl_xor(a2, d, 64);
        a3 += __shfl_xor(a3, d, 64);
        S  += __shfl_xor(S,  d, 64);
    }

    if (lane < 8) {
        const float c128 = 128.0f * S;
        const int f0 = sh * 16 + 2 * u;          // bytes 4u,4u+2 -> a0,a2
        const int f1 = (sh + 8) * 16 + 2 * u;    // bytes 4u+1,4u+3 -> a1,a3
        f32x2 o0, o1;
        o0.x = a0 - c128 + bias[f0];  o0.y = a2 - c128 + bias[f0 + 1];
        o1.x = a1 - c128 + bias[f1];  o1.y = a3 - c128 + bias[f1 + 1];
        __builtin_nontemporal_store(o0, reinterpret_cast<f32x2*>(out + (size_t)row * NF + f0));
        __builtin_nontemporal_store(o1, reinterpret_cast<f32x2*>(out + (size_t)row * NF + f1));
    }
}

extern "C" void kernel_launch(void* const* d_in, const int* in_sizes, int n_in,
                              void* d_out, int out_size, void* d_ws, size_t ws_size,
                              hipStream_t stream) {
    const float* x    = (const float*)d_in[0];
    const int*   erow = (const int*)d_in[1];
    const int*   ecol = (const int*)d_in[2];
    const float* eval = (const float*)d_in[3];
    const float* w    = (const float*)d_in[4];
    const float* bias = (const float*)d_in[5];
    float*       out  = (float*)d_out;

    unsigned char* tabS   = (unsigned char*)d_ws;                      // 25,600,000 B
    int*           rowptr = (int*)((char*)d_ws + 25600000);            //    400,004 B
    __bf16*        wfrag  = (__bf16*)((char*)d_ws + 26000016);         //    131,072 B
    float*         scales = (float*)((char*)d_ws + 26131088);          //    400,000 B

    prep_w<<<32, 256, 0, stream>>>(w, wfrag);
    gemm_q<<<GEMM_BLOCKS + RP_BLOCKS, 320, 0, stream>>>(x, wfrag, tabS, scales,
                                                        erow, rowptr);
    spmm_s<<<8 * (NN / 4), 256, 0, stream>>>(tabS, rowptr, ecol, eval, scales,
                                             bias, out);
}

// Round 19
// 180.041 us; speedup vs baseline: 2.3436x; 2.3436x over previous
//
#include <hip/hip_runtime.h>
#include <hip/hip_bf16.h>

#define NN 100000      // nodes
#define NE 3200000     // edges
#define NF 256         // features
#define CHUNK 512      // staged edges per block iteration
#define GEMM_BLOCKS 1250          // NN/80
#define RP_BLOCKS   1250          // ceil((NE/8)/320)

typedef __attribute__((ext_vector_type(8))) __bf16 bf16x8;
typedef __attribute__((ext_vector_type(4))) float  f32x4;
typedef __attribute__((ext_vector_type(4))) int    i32x4;

// Table layout (per node, 256 B): byte p holds feature feat(p) = (p&15)*16 + (p>>4)
// (16x16 transpose), stored BIASED: byte = q + 128 (u8). spmm: sum(v*u) - 128*sum(v).

// ---- prep: W -> per-lane MFMA B-fragments (bf16) + permuted bias ----
__global__ __launch_bounds__(256) void prep_w(const float* __restrict__ w,
                                              __bf16* __restrict__ wfrag,
                                              const float* __restrict__ bias,
                                              float* __restrict__ bias_p) {
    if (blockIdx.x == 32) {          // permuted bias: bias_p[4l+b] = bias[F(l,b)]
        const int t = threadIdx.x;
        const int l = t >> 2, b = t & 3;
        bias_p[t] = bias[(l & 3) * 64 + 16 * b + (l >> 2)];
        return;
    }
    const int t = blockIdx.x * 256 + threadIdx.x;   // 8192 total
    const int lane = t & 63;
    const int nf   = (t >> 6) & 15;
    const int ks   = t >> 10;
    const int col  = nf * 16 + (lane & 15);
    const int k0   = ks * 32 + (lane >> 4) * 8;
    bf16x8 v;
#pragma unroll
    for (int j = 0; j < 8; ++j) v[j] = (__bf16)w[(k0 + j) * NF + col];
    reinterpret_cast<bf16x8*>(wfrag)[t] = v;
}

// ---- fused GEMM + u8 quantize; B-fragments LDS-staged (5x reuse per block) ----
__global__ __launch_bounds__(320) void gemm_q(const float* __restrict__ x,
                                              const __bf16* __restrict__ wfrag,
                                              unsigned char* __restrict__ tab,
                                              float* __restrict__ scales,
                                              const int* __restrict__ erow,
                                              int* __restrict__ rowptr) {
    if (blockIdx.x >= GEMM_BLOCKS) {             // rowptr rider: 8 edges/thread
        const int t8 = (blockIdx.x - GEMM_BLOCKS) * 320 + threadIdx.x;
        if (t8 >= NE / 8) return;
        const int base = t8 * 8;
        const i32x4 c0 = *reinterpret_cast<const i32x4*>(erow + base);
        const i32x4 c1 = *reinterpret_cast<const i32x4*>(erow + base + 4);
        const int E[8] = {c0.x, c0.y, c0.z, c0.w, c1.x, c1.y, c1.z, c1.w};
        int prev = (base == 0) ? -1 : erow[base - 1];
#pragma unroll
        for (int j = 0; j < 8; ++j) {
            const int r = E[j];
            for (int q = prev + 1; q <= r; ++q) rowptr[q] = base + j;
            prev = r;
        }
        if (base + 8 == NE) {
            for (int q = prev + 1; q <= NN; ++q) rowptr[q] = NE;
        }
        return;
    }

    __shared__ __align__(16) __bf16 As[80 * 72];   // 11.5 KB, row stride 144 B
    __shared__ __align__(16) bf16x8 Bs[2048];      // 32 KB: one phase's B-slice

    const int t    = threadIdx.x;
    const int wv   = t >> 6;
    const int lane = t & 63;
    const int row0 = blockIdx.x * 80;

    f32x4 acc[16];
#pragma unroll
    for (int nf = 0; nf < 16; ++nf) acc[nf] = (f32x4){0.f, 0.f, 0.f, 0.f};

    const int    srow = t >> 2;
    const int    sc   = (t & 3) * 16;
    const float* xp   = x + (size_t)(row0 + srow) * NF + sc;
    char* const  wr   = reinterpret_cast<char*>(As) + srow * 144 + sc * 2;

    const char* const rd =
        reinterpret_cast<const char*>(As) + (wv * 16 + (lane & 15)) * 144 + ((lane >> 4) << 4);

    const bf16x8* wf = reinterpret_cast<const bf16x8*>(wfrag);

    f32x4 s0 = __builtin_nontemporal_load(reinterpret_cast<const f32x4*>(xp));
    f32x4 s1 = __builtin_nontemporal_load(reinterpret_cast<const f32x4*>(xp + 4));
    f32x4 s2 = __builtin_nontemporal_load(reinterpret_cast<const f32x4*>(xp + 8));
    f32x4 s3 = __builtin_nontemporal_load(reinterpret_cast<const f32x4*>(xp + 12));

    for (int p = 0; p < 4; ++p) {
        // stage this phase's 32 KB B-slice (contiguous, coalesced, L2-hot)
        for (int i = t; i < 2048; i += 320) Bs[i] = wf[p * 2048 + i];

        bf16x8 b0, b1;
        b0[0] = (__bf16)s0.x; b0[1] = (__bf16)s0.y; b0[2] = (__bf16)s0.z; b0[3] = (__bf16)s0.w;
        b0[4] = (__bf16)s1.x; b0[5] = (__bf16)s1.y; b0[6] = (__bf16)s1.z; b0[7] = (__bf16)s1.w;
        b1[0] = (__bf16)s2.x; b1[1] = (__bf16)s2.y; b1[2] = (__bf16)s2.z; b1[3] = (__bf16)s2.w;
        b1[4] = (__bf16)s3.x; b1[5] = (__bf16)s3.y; b1[6] = (__bf16)s3.z; b1[7] = (__bf16)s3.w;
        *reinterpret_cast<bf16x8*>(wr)      = b0;   // ds_write_b128
        *reinterpret_cast<bf16x8*>(wr + 16) = b1;
        __syncthreads();

        if (p < 3) {
            const float* nx = xp + (p + 1) * 64;
            s0 = __builtin_nontemporal_load(reinterpret_cast<const f32x4*>(nx));
            s1 = __builtin_nontemporal_load(reinterpret_cast<const f32x4*>(nx + 4));
            s2 = __builtin_nontemporal_load(reinterpret_cast<const f32x4*>(nx + 8));
            s3 = __builtin_nontemporal_load(reinterpret_cast<const f32x4*>(nx + 12));
        }

        const bf16x8 af0 = *reinterpret_cast<const bf16x8*>(rd);        // ksub 0
        const bf16x8 af1 = *reinterpret_cast<const bf16x8*>(rd + 64);   // ksub 1
#pragma unroll
        for (int nf = 0; nf < 16; ++nf) {
            const bf16x8 w0 = Bs[(0 * 16 + nf) * 64 + lane];            // ds_read_b128
            acc[nf] = __builtin_amdgcn_mfma_f32_16x16x32_bf16(af0, w0, acc[nf], 0, 0, 0);
        }
#pragma unroll
        for (int nf = 0; nf < 16; ++nf) {
            const bf16x8 w1 = Bs[(1 * 16 + nf) * 64 + lane];
            acc[nf] = __builtin_amdgcn_mfma_f32_16x16x32_bf16(af1, w1, acc[nf], 0, 0, 0);
        }
        __syncthreads();
    }

    // Epilogue: per-row absmax -> biased u8, packed 16 B/lane (transposed layout).
    const int hi   = lane >> 4;
    const int ccol = lane & 15;

    float m[4];
#pragma unroll
    for (int r = 0; r < 4; ++r) {
        float mm = 0.f;
#pragma unroll
        for (int nf = 0; nf < 16; ++nf) mm = fmaxf(mm, fabsf(acc[nf][r]));
        m[r] = mm;
    }
#pragma unroll
    for (int w = 1; w < 16; w <<= 1) {
#pragma unroll
        for (int r = 0; r < 4; ++r) m[r] = fmaxf(m[r], __shfl_xor(m[r], w, 64));
    }

#pragma unroll
    for (int r = 0; r < 4; ++r) {
        const int   node = row0 + wv * 16 + hi * 4 + r;
        const float isc  = 127.0f / fmaxf(m[r], 1e-30f);
        uint4 pk = {0u, 0u, 0u, 0u};
        unsigned int* pw = reinterpret_cast<unsigned int*>(&pk);
#pragma unroll
        for (int nf = 0; nf < 16; ++nf) {
            const int q = (int)rintf(acc[nf][r] * isc) + 128;   // biased u8
            pw[nf >> 2] |= ((unsigned int)(q & 0xff)) << ((nf & 3) * 8);
        }
        *reinterpret_cast<uint4*>(tab + (size_t)node * 256 + ccol * 16) = pk;
        if (ccol == 0) scales[node] = m[r] * (1.0f / 127.0f);
    }
}

// ---- spmm fused (R13-verified, 123 µs): LDS edge stream + u8 table gather ----
__global__ __launch_bounds__(256) void spmm_f(const unsigned int* __restrict__ tab32,
                                              const int* __restrict__ rowptr,
                                              const int* __restrict__ ecol,
                                              const float* __restrict__ eval,
                                              const float* __restrict__ scales,
                                              const float* __restrict__ bias_p,
                                              float* __restrict__ out) {
    __shared__ int2 buf[CHUNK];

    const int wave = threadIdx.x >> 6;
    const int lane = threadIdx.x & 63;
    const int row  = blockIdx.x * 4 + wave;

    const int bs   = rowptr[blockIdx.x * 4];
    const int bend = rowptr[blockIdx.x * 4 + 4];
    const int rs   = rowptr[row];
    const int re   = rowptr[row + 1];

    float a0 = 0.f, a1 = 0.f, a2 = 0.f, a3 = 0.f, S = 0.f;

    for (int cs = bs; cs < bend; cs += CHUNK) {
        const int cnt = min(CHUNK, bend - cs);
        if (cs != bs) __syncthreads();             // protect buf reuse
        for (int j = threadIdx.x; j < cnt; j += 256) {
            const int   c = ecol[cs + j];          // coalesced
            const float v = eval[cs + j];          // coalesced
            buf[j] = make_int2(c, __float_as_int(v * scales[c]));  // scales L2-hot
        }
        __syncthreads();

        const int lo = max(rs, cs);
        const int hi = min(re, cs + cnt);
#pragma unroll 4
        for (int i = lo; i < hi; ++i) {
            const int2  p = buf[i - cs];           // ds_read_b64 broadcast
            const float v = __int_as_float(p.y);
            const unsigned int g = tab32[((unsigned)p.x << 6) + lane];
            a0 = fmaf(v, (float)(g & 0xffu), a0);
            a1 = fmaf(v, (float)((g >> 8) & 0xffu), a1);
            a2 = fmaf(v, (float)((g >> 16) & 0xffu), a2);
            a3 = fmaf(v, (float)(g >> 24), a3);
            S += v;
        }
    }

    // unbias: a - 128*S ; lane's features F(b) = (lane&3)*64 + 16b + (lane>>2)
    const f32x4 bp = *reinterpret_cast<const f32x4*>(bias_p + lane * 4);
    const float c128 = 128.0f * S;
    float* op = out + (size_t)row * NF + (lane & 3) * 64 + (lane >> 2);
    __builtin_nontemporal_store(a0 - c128 + bp.x, op);
    __builtin_nontemporal_store(a1 - c128 + bp.y, op + 16);
    __builtin_nontemporal_store(a2 - c128 + bp.z, op + 32);
    __builtin_nontemporal_store(a3 - c128 + bp.w, op + 48);
}

extern "C" void kernel_launch(void* const* d_in, const int* in_sizes, int n_in,
                              void* d_out, int out_size, void* d_ws, size_t ws_size,
                              hipStream_t stream) {
    const float* x    = (const float*)d_in[0];
    const int*   erow = (const int*)d_in[1];
    const int*   ecol = (const int*)d_in[2];
    const float* eval = (const float*)d_in[3];
    const float* w    = (const float*)d_in[4];
    const float* bias = (const float*)d_in[5];
    float*       out  = (float*)d_out;

    unsigned char* tab    = (unsigned char*)d_ws;                      // 25,600,000 B
    int*           rowptr = (int*)((char*)d_ws + 25600000);            //    400,004 B
    __bf16*        wfrag  = (__bf16*)((char*)d_ws + 26000016);         //    131,072 B
    float*         scales = (float*)((char*)d_ws + 26131088);          //    400,000 B
    float*         bias_p = (float*)((char*)d_ws + 26531088);          //      1,024 B

    prep_w<<<33, 256, 0, stream>>>(w, wfrag, bias, bias_p);
    gemm_q<<<GEMM_BLOCKS + RP_BLOCKS, 320, 0, stream>>>(x, wfrag, tab, scales,
                                                        erow, rowptr);
    spmm_f<<<NN / 4, 256, 0, stream>>>(
        reinterpret_cast<const unsigned int*>(tab), rowptr, ecol, eval, scales,
        bias_p, out);
}